// Round 1
// baseline (891.904 us; speedup 1.0000x reference)
//
#include <hip/hip_runtime.h>
#include <hip/hip_bf16.h>

// Problem constants (match reference setup_inputs)
#define N_NODES 50000
#define E_EDGES 600000
#define C_CH    130
#define CP      160      // padded channel width (MFMA-friendly, float4-aligned)
#define L_LAYERS 4
#define BN_EPS  1e-5f

// ---------------------------------------------------------------------------
// small utility kernels
// ---------------------------------------------------------------------------
__global__ void k_zero_i32(int* p, int n) {
    int i = blockIdx.x * blockDim.x + threadIdx.x;
    for (; i < n; i += gridDim.x * blockDim.x) p[i] = 0;
}

// pad a [rows][cols] fp32 matrix into [160][160] (zeros elsewhere)
__global__ void k_padW(const float* __restrict__ src, float* __restrict__ dst,
                       int rows, int cols) {
    int r = blockIdx.x;            // 0..159
    int c = threadIdx.x;           // block 192, guard
    if (c >= CP) return;
    dst[r * CP + c] = (r < rows && c < cols) ? src[r * cols + c] : 0.f;
}

// pad Wh2 [130][2] -> [160][2]
__global__ void k_padWh2(const float* __restrict__ src, float* __restrict__ dst) {
    int i = threadIdx.x;           // one block of 384, 320 valid
    if (i >= CP * 2) return;
    int r = i >> 1, c = i & 1;
    dst[i] = (r < C_CH) ? src[r * 2 + c] : 0.f;
}

// Per-GEMM epilogue scale/shift: layout ss[g][2][160], g = 0..8
// g even (=2l):  scale=1, shift=b1[l]           (GEMM1 + relu)
// g odd  (=2l+1): scale=gamma*rsqrt(var+eps), shift=(b2-mean)*scale+beta (GEMM2+BN+relu)
// g==8:          scale=1, shift=bh1             (head GEMM1 + relu)
__global__ void k_ss(const float* __restrict__ b1, const float* __restrict__ b2,
                     const float* __restrict__ gamma, const float* __restrict__ beta,
                     const float* __restrict__ rmean, const float* __restrict__ rvar,
                     const float* __restrict__ bh1, float* __restrict__ ss) {
    int g = blockIdx.x;
    int c = threadIdx.x;
    if (c >= CP) return;
    float scale = 1.f, shift = 0.f;
    if (g < 2 * L_LAYERS) {
        int l = g >> 1;
        if ((g & 1) == 0) {
            if (c < C_CH) shift = b1[l * C_CH + c];
        } else if (c < C_CH) {
            float s = gamma[l * C_CH + c] * rsqrtf(rvar[l * C_CH + c] + BN_EPS);
            scale = s;
            shift = (b2[l * C_CH + c] - rmean[l * C_CH + c]) * s + beta[l * C_CH + c];
        }
    } else {
        if (c < C_CH) shift = bh1[c];
    }
    ss[(g * 2 + 0) * CP + c] = scale;
    ss[(g * 2 + 1) * CP + c] = shift;
}

// build node features h0[N][CP]: [one_hot(type,32) | one_hot(clip(tok),96) | x_small(2) | 0-pad]
__global__ void k_feat(const int* __restrict__ xt, const int* __restrict__ xk,
                       const float* __restrict__ xs, float* __restrict__ h) {
    int n = blockIdx.x;
    int c = threadIdx.x;
    if (c >= CP) return;
    float v = 0.f;
    if (c < 32) {
        v = (xt[n] == c) ? 1.f : 0.f;
    } else if (c < 128) {
        int tk = xk[n];
        tk = tk < 0 ? 0 : (tk > 95 ? 95 : tk);
        v = (tk == c - 32) ? 1.f : 0.f;
    } else if (c < C_CH) {
        v = xs[n * 2 + (c - 128)];
    }
    h[(size_t)n * CP + c] = v;
}

// ---------------------------------------------------------------------------
// CSR-by-dst build
// ---------------------------------------------------------------------------
__global__ void k_indeg(const int* __restrict__ dst, int* __restrict__ indeg) {
    int e = blockIdx.x * blockDim.x + threadIdx.x;
    if (e < E_EDGES) atomicAdd(&indeg[dst[e]], 1);
}

// 2-level exclusive scan over N=50000 in 1024-element blocks
__global__ void k_scan1(const int* __restrict__ indeg, int* __restrict__ localscan,
                        int* __restrict__ bsum) {
    __shared__ int lds[256];
    int tid = threadIdx.x;
    int base = blockIdx.x * 1024 + tid * 4;
    int v[4]; int s = 0;
#pragma unroll
    for (int r = 0; r < 4; r++) {
        int i = base + r;
        v[r] = (i < N_NODES) ? indeg[i] : 0;
        s += v[r];
    }
    lds[tid] = s;
    __syncthreads();
    for (int off = 1; off < 256; off <<= 1) {
        int x = (tid >= off) ? lds[tid - off] : 0;
        __syncthreads();
        lds[tid] += x;
        __syncthreads();
    }
    int excl = lds[tid] - s;
    int w = excl;
#pragma unroll
    for (int r = 0; r < 4; r++) {
        int i = base + r;
        if (i < N_NODES) localscan[i] = w;
        w += v[r];
    }
    if (tid == 255) bsum[blockIdx.x] = lds[255];
}

__global__ void k_scan2(const int* __restrict__ bsum, int* __restrict__ boff, int nb) {
    if (threadIdx.x == 0 && blockIdx.x == 0) {
        int run = 0;
        for (int b = 0; b < nb; b++) { boff[b] = run; run += bsum[b]; }
    }
}

__global__ void k_scan3(int* __restrict__ rowstart, const int* __restrict__ boff) {
    int tid = threadIdx.x;
    int base = blockIdx.x * 1024 + tid * 4;
    int add = boff[blockIdx.x];
#pragma unroll
    for (int r = 0; r < 4; r++) {
        int i = base + r;
        if (i < N_NODES) rowstart[i] += add;
    }
    if (blockIdx.x == 0 && tid == 0) rowstart[N_NODES] = E_EDGES;
}

// fill CSR: csr[pos] = src | (etype<<16)  (src < 50000 < 2^16)
__global__ void k_fill(const int* __restrict__ src, const int* __restrict__ dst,
                       const int* __restrict__ et, const int* __restrict__ rowstart,
                       int* __restrict__ cursor, int* __restrict__ csr) {
    int e = blockIdx.x * blockDim.x + threadIdx.x;
    if (e >= E_EDGES) return;
    int d = dst[e];
    int pos = atomicAdd(&cursor[d], 1);
    csr[rowstart[d] + pos] = (src[e] & 0xFFFF) | (et[e] << 16);
}

// ---------------------------------------------------------------------------
// SpMM-like aggregation: z[n] = h[n] + sum_{e: dst=n} relu(h[src_e] + onehot(etype_e))
// one wave (64 lanes) per node; lane holds channels {lane, lane+64, lane+128(<130)}
// ---------------------------------------------------------------------------
__global__ __launch_bounds__(256) void k_spmm(const float* __restrict__ h,
                                              const int* __restrict__ rowstart,
                                              const int* __restrict__ csr,
                                              float* __restrict__ z) {
    int wave = threadIdx.x >> 6;
    int lane = threadIdx.x & 63;
    int n = blockIdx.x * 4 + wave;
    if (n >= N_NODES) return;
    int rs = rowstart[n];
    int re = rowstart[n + 1];
    float a0 = 0.f, a1 = 0.f, a2 = 0.f;
    for (int e = rs; e < re; ++e) {
        int p = csr[e];
        int s = p & 0xFFFF;
        int t = p >> 16;
        const float* hr = h + (size_t)s * CP;
        float v0 = hr[lane] + ((lane == t) ? 1.f : 0.f);  // etype in [0,3) => lane range
        float v1 = hr[64 + lane];
        float v2 = (lane < 2) ? hr[128 + lane] : 0.f;
        a0 += fmaxf(v0, 0.f);
        a1 += fmaxf(v1, 0.f);
        a2 += fmaxf(v2, 0.f);
    }
    const float* hn = h + (size_t)n * CP;
    float* zr = z + (size_t)n * CP;
    zr[lane] = hn[lane] + a0;
    zr[64 + lane] = hn[64 + lane] + a1;
    if (lane < 32) zr[128 + lane] = (lane < 2) ? (hn[128 + lane] + a2) : 0.f;
}

// ---------------------------------------------------------------------------
// fp32 GEMM: Cout[M][CP] = relu( A[M][CP] @ Wp[160][160] * scale + shift )
// tile 64 rows x 160 cols, K_STEP 32, micro-tile 4x10 per thread (16x16 grid)
// ---------------------------------------------------------------------------
__global__ __launch_bounds__(256) void k_gemm(const float* __restrict__ A,
                                              const float* __restrict__ Wp,
                                              const float* __restrict__ scale,
                                              const float* __restrict__ shift,
                                              float* __restrict__ Cout, int M) {
    __shared__ float As[64 * 36];      // pad stride 36 (2-way conflict only)
    __shared__ float Bs[32 * 160];
    int tid = threadIdx.x;
    int tx = tid & 15;                  // col group: 10 cols each
    int ty = tid >> 4;                  // row group: 4 rows each
    int mBase = blockIdx.x * 64;
    float acc[4][10] = {};

    for (int ks = 0; ks < 5; ++ks) {
        // A tile: 64x32 floats = 512 float4 -> 2 per thread
#pragma unroll
        for (int r = 0; r < 2; r++) {
            int q = tid + 256 * r;
            int m = q >> 3;
            int k4 = q & 7;
            int gm = mBase + m;
            float4 v = make_float4(0.f, 0.f, 0.f, 0.f);
            if (gm < M) v = *(const float4*)(A + (size_t)gm * CP + ks * 32 + k4 * 4);
            *(float4*)(&As[m * 36 + k4 * 4]) = v;
        }
        // B tile: 32x160 floats = 1280 float4 -> 5 per thread
#pragma unroll
        for (int r = 0; r < 5; r++) {
            int q = tid + 256 * r;
            int k = q / 40;
            int c4 = q % 40;
            float4 v = *(const float4*)(Wp + (size_t)(ks * 32 + k) * CP + c4 * 4);
            *(float4*)(&Bs[k * CP + c4 * 4]) = v;
        }
        __syncthreads();
#pragma unroll
        for (int kk = 0; kk < 32; ++kk) {
            float a[4], b[10];
#pragma unroll
            for (int i = 0; i < 4; i++) a[i] = As[(ty * 4 + i) * 36 + kk];
#pragma unroll
            for (int j = 0; j < 10; j++) b[j] = Bs[kk * CP + tx * 10 + j];
#pragma unroll
            for (int i = 0; i < 4; i++)
#pragma unroll
                for (int j = 0; j < 10; j++) acc[i][j] = fmaf(a[i], b[j], acc[i][j]);
        }
        __syncthreads();
    }

    float sc[10], sh[10];
#pragma unroll
    for (int j = 0; j < 10; j++) {
        sc[j] = scale[tx * 10 + j];
        sh[j] = shift[tx * 10 + j];
    }
#pragma unroll
    for (int i = 0; i < 4; i++) {
        int gm = mBase + ty * 4 + i;
        if (gm < M) {
            float* o = Cout + (size_t)gm * CP + tx * 10;
#pragma unroll
            for (int j = 0; j < 10; j++)
                o[j] = fmaxf(fmaf(acc[i][j], sc[j], sh[j]), 0.f);
        }
    }
}

// head second matmul: out[n][k] = sum_j u[n][j]*Wh2p[j][k] + bh2[k]   (no relu)
__global__ __launch_bounds__(256) void k_head2(const float* __restrict__ U,
                                               const float* __restrict__ W2p,
                                               const float* __restrict__ bh2,
                                               float* __restrict__ out) {
    int wave = threadIdx.x >> 6;
    int lane = threadIdx.x & 63;
    int n = blockIdx.x * 4 + wave;
    if (n >= N_NODES) return;
    const float* u = U + (size_t)n * CP;
    float u0 = u[lane], u1 = u[64 + lane];
    float u2 = (lane < 32) ? u[128 + lane] : 0.f;
    float w00 = W2p[lane * 2], w01 = W2p[lane * 2 + 1];
    float w10 = W2p[(64 + lane) * 2], w11 = W2p[(64 + lane) * 2 + 1];
    float w20 = (lane < 32) ? W2p[(128 + lane) * 2] : 0.f;
    float w21 = (lane < 32) ? W2p[(128 + lane) * 2 + 1] : 0.f;
    float p0 = u0 * w00 + u1 * w10 + u2 * w20;
    float p1 = u0 * w01 + u1 * w11 + u2 * w21;
#pragma unroll
    for (int off = 32; off > 0; off >>= 1) {
        p0 += __shfl_down(p0, off, 64);
        p1 += __shfl_down(p1, off, 64);
    }
    if (lane == 0) {
        out[n * 2 + 0] = p0 + bh2[0];
        out[n * 2 + 1] = p1 + bh2[1];
    }
}

// ---------------------------------------------------------------------------
extern "C" void kernel_launch(void* const* d_in, const int* in_sizes, int n_in,
                              void* d_out, int out_size, void* d_ws, size_t ws_size,
                              hipStream_t stream) {
    const int* x_type  = (const int*)d_in[0];
    const int* x_tok   = (const int*)d_in[1];
    const float* x_small = (const float*)d_in[2];
    const int* e_src   = (const int*)d_in[3];
    const int* e_dst   = e_src + E_EDGES;
    const int* e_type  = (const int*)d_in[4];
    // d_in[5] = batch (unused; pooling result discarded by reference)
    const float* W1    = (const float*)d_in[6];
    const float* b1    = (const float*)d_in[7];
    const float* W2    = (const float*)d_in[8];
    const float* b2    = (const float*)d_in[9];
    const float* gamma = (const float*)d_in[10];
    const float* beta  = (const float*)d_in[11];
    const float* rmean = (const float*)d_in[12];
    const float* rvar  = (const float*)d_in[13];
    const float* Wh1   = (const float*)d_in[14];
    const float* bh1   = (const float*)d_in[15];
    const float* Wh2   = (const float*)d_in[16];
    const float* bh2   = (const float*)d_in[17];
    float* out = (float*)d_out;

    // workspace carve-up (deterministic every call)
    char* ws = (char*)d_ws;
    size_t o = 0;
    auto take = [&](size_t bytes) -> void* {
        void* p = ws + o;
        o = (o + bytes + 255) & ~(size_t)255;
        return p;
    };
    const size_t NODE_BUF = (size_t)N_NODES * CP * sizeof(float);  // 32 MB
    float* bufA = (float*)take(NODE_BUF);   // h
    float* bufB = (float*)take(NODE_BUF);   // z / u
    float* bufC = (float*)take(NODE_BUF);   // t
    float* Wp   = (float*)take((size_t)9 * CP * CP * sizeof(float));  // 9 padded weights
    float* Wh2p = (float*)take((size_t)CP * 2 * sizeof(float));
    float* ss   = (float*)take((size_t)9 * 2 * CP * sizeof(float));
    int* indeg    = (int*)take((size_t)N_NODES * sizeof(int));
    int* cursor   = (int*)take((size_t)N_NODES * sizeof(int));
    int* rowstart = (int*)take((size_t)(N_NODES + 1) * sizeof(int));
    int* bsum     = (int*)take(64 * sizeof(int));
    int* boff     = (int*)take(64 * sizeof(int));
    int* csr      = (int*)take((size_t)E_EDGES * sizeof(int));
    (void)ws_size; (void)in_sizes; (void)n_in; (void)out_size;

    const int NB_SCAN = (N_NODES + 1023) / 1024;  // 49

    // --- weight/epilogue prep ---
    for (int l = 0; l < L_LAYERS; l++) {
        k_padW<<<CP, 192, 0, stream>>>(W1 + (size_t)l * C_CH * C_CH, Wp + (size_t)(2 * l) * CP * CP, C_CH, C_CH);
        k_padW<<<CP, 192, 0, stream>>>(W2 + (size_t)l * C_CH * C_CH, Wp + (size_t)(2 * l + 1) * CP * CP, C_CH, C_CH);
    }
    k_padW<<<CP, 192, 0, stream>>>(Wh1, Wp + (size_t)8 * CP * CP, C_CH, C_CH);
    k_padWh2<<<1, 384, 0, stream>>>(Wh2, Wh2p);
    k_ss<<<9, 192, 0, stream>>>(b1, b2, gamma, beta, rmean, rvar, bh1, ss);

    // --- features ---
    k_feat<<<N_NODES, 192, 0, stream>>>(x_type, x_tok, x_small, bufA);

    // --- CSR by dst ---
    k_zero_i32<<<(N_NODES + 255) / 256, 256, 0, stream>>>(indeg, N_NODES);
    k_zero_i32<<<(N_NODES + 255) / 256, 256, 0, stream>>>(cursor, N_NODES);
    k_indeg<<<(E_EDGES + 255) / 256, 256, 0, stream>>>(e_dst, indeg);
    k_scan1<<<NB_SCAN, 256, 0, stream>>>(indeg, rowstart, bsum);
    k_scan2<<<1, 64, 0, stream>>>(bsum, boff, NB_SCAN);
    k_scan3<<<NB_SCAN, 256, 0, stream>>>(rowstart, boff);
    k_fill<<<(E_EDGES + 255) / 256, 256, 0, stream>>>(e_src, e_dst, e_type, rowstart, cursor, csr);

    // --- layers ---
    const int GEMM_GRID = (N_NODES + 63) / 64;  // 782
    for (int l = 0; l < L_LAYERS; l++) {
        k_spmm<<<(N_NODES + 3) / 4, 256, 0, stream>>>(bufA, rowstart, csr, bufB);
        k_gemm<<<GEMM_GRID, 256, 0, stream>>>(bufB, Wp + (size_t)(2 * l) * CP * CP,
                                              ss + (size_t)(2 * (2 * l)) * CP,
                                              ss + (size_t)(2 * (2 * l) + 1) * CP,
                                              bufC, N_NODES);
        k_gemm<<<GEMM_GRID, 256, 0, stream>>>(bufC, Wp + (size_t)(2 * l + 1) * CP * CP,
                                              ss + (size_t)(2 * (2 * l + 1)) * CP,
                                              ss + (size_t)(2 * (2 * l + 1) + 1) * CP,
                                              bufA, N_NODES);
    }

    // --- head ---
    k_gemm<<<GEMM_GRID, 256, 0, stream>>>(bufA, Wp + (size_t)8 * CP * CP,
                                          ss + (size_t)(2 * 8) * CP,
                                          ss + (size_t)(2 * 8 + 1) * CP,
                                          bufB, N_NODES);
    k_head2<<<(N_NODES + 3) / 4, 256, 0, stream>>>(bufB, Wh2p, bh2, out);
}

// Round 2
// 418.331 us; speedup vs baseline: 2.1321x; 2.1321x over previous
//
#include <hip/hip_runtime.h>
#include <hip/hip_bf16.h>

// Problem constants (match reference setup_inputs)
#define N_NODES 50000
#define E_EDGES 600000
#define C_CH    130
#define CP      160      // padded channel width
#define L_LAYERS 4
#define BN_EPS  1e-5f

typedef __bf16 bf16x8 __attribute__((ext_vector_type(8)));
typedef float  f32x4  __attribute__((ext_vector_type(4)));

// fp32 -> bf16 RNE
__device__ __forceinline__ unsigned short f2bf(float f) {
    unsigned u = __float_as_uint(f);
    unsigned r = (u + 0x7FFFu + ((u >> 16) & 1u)) >> 16;
    return (unsigned short)r;
}
__device__ __forceinline__ unsigned packbf(float lo, float hi) {
    return (unsigned)f2bf(lo) | ((unsigned)f2bf(hi) << 16);
}
__device__ __forceinline__ float bflo(unsigned d) { return __uint_as_float(d << 16); }
__device__ __forceinline__ float bfhi(unsigned d) { return __uint_as_float(d & 0xFFFF0000u); }

// ---------------------------------------------------------------------------
// small utility kernels
// ---------------------------------------------------------------------------
__global__ void k_zero_i32(int* p, int n) {
    int i = blockIdx.x * blockDim.x + threadIdx.x;
    for (; i < n; i += gridDim.x * blockDim.x) p[i] = 0;
}

// pad Wh2 [130][2] -> [160][2] fp32
__global__ void k_padWh2(const float* __restrict__ src, float* __restrict__ dst) {
    int i = threadIdx.x;
    if (i >= CP * 2) return;
    int r = i >> 1, c = i & 1;
    dst[i] = (r < C_CH) ? src[r * 2 + c] : 0.f;
}

// Per-GEMM epilogue scale/shift: ss[g][2][160], g = 0..8
__global__ void k_ss(const float* __restrict__ b1, const float* __restrict__ b2,
                     const float* __restrict__ gamma, const float* __restrict__ beta,
                     const float* __restrict__ rmean, const float* __restrict__ rvar,
                     const float* __restrict__ bh1, float* __restrict__ ss) {
    int g = blockIdx.x;
    int c = threadIdx.x;
    if (c >= CP) return;
    float scale = 1.f, shift = 0.f;
    if (g < 2 * L_LAYERS) {
        int l = g >> 1;
        if ((g & 1) == 0) {
            if (c < C_CH) shift = b1[l * C_CH + c];
        } else if (c < C_CH) {
            float s = gamma[l * C_CH + c] * rsqrtf(rvar[l * C_CH + c] + BN_EPS);
            scale = s;
            shift = (b2[l * C_CH + c] - rmean[l * C_CH + c]) * s + beta[l * C_CH + c];
        }
    } else {
        if (c < C_CH) shift = bh1[c];
    }
    ss[(g * 2 + 0) * CP + c] = scale;
    ss[(g * 2 + 1) * CP + c] = shift;
}

// Pack weights into MFMA B-fragment order, bf16.
// Bp[frag = g*50 + ks*10 + f][lane][j] = W_g[k = ks*32 + (lane>>4)*8 + j][c = f*16 + (lane&15)]
__global__ void k_packB(const float* __restrict__ W1, const float* __restrict__ W2,
                        const float* __restrict__ Wh1, unsigned short* __restrict__ Bp) {
    int blk = blockIdx.x;          // 0..449
    int g = blk / 50;
    int r = blk - g * 50;
    int ks = r / 10, f = r - ks * 10;
    int l = threadIdx.x;           // 0..63
    const float* W;
    if (g < 8) W = (g & 1) ? (W2 + (size_t)(g >> 1) * C_CH * C_CH)
                           : (W1 + (size_t)(g >> 1) * C_CH * C_CH);
    else       W = Wh1;
    int kg = l >> 4;
    int c = f * 16 + (l & 15);
    union { unsigned short s[8]; uint4 u; } out;
#pragma unroll
    for (int j = 0; j < 8; j++) {
        int k = ks * 32 + kg * 8 + j;
        float v = (k < C_CH && c < C_CH) ? W[k * C_CH + c] : 0.f;
        out.s[j] = f2bf(v);
    }
    *(uint4*)(Bp + ((size_t)(blk * 64 + l) * 8)) = out.u;
}

// node features h0 as bf16, 80 dwords (160 bf16) per row
__global__ void k_feat(const int* __restrict__ xt, const int* __restrict__ xk,
                       const float* __restrict__ xs, unsigned* __restrict__ h2) {
    int idx = blockIdx.x * blockDim.x + threadIdx.x;
    if (idx >= N_NODES * 80) return;
    int n = idx / 80;
    int d = idx - n * 80;
    float v[2];
#pragma unroll
    for (int s = 0; s < 2; s++) {
        int c = 2 * d + s;
        float x = 0.f;
        if (c < 32) {
            x = (xt[n] == c) ? 1.f : 0.f;
        } else if (c < 128) {
            int tk = xk[n];
            tk = tk < 0 ? 0 : (tk > 95 ? 95 : tk);
            x = (tk == c - 32) ? 1.f : 0.f;
        } else if (c < C_CH) {
            x = xs[n * 2 + (c - 128)];
        }
        v[s] = x;
    }
    h2[idx] = packbf(v[0], v[1]);
}

// ---------------------------------------------------------------------------
// CSR-by-dst build
// ---------------------------------------------------------------------------
__global__ void k_indeg(const int* __restrict__ dst, int* __restrict__ indeg) {
    int e = blockIdx.x * blockDim.x + threadIdx.x;
    if (e < E_EDGES) atomicAdd(&indeg[dst[e]], 1);
}

__global__ void k_scan1(const int* __restrict__ indeg, int* __restrict__ localscan,
                        int* __restrict__ bsum) {
    __shared__ int lds[256];
    int tid = threadIdx.x;
    int base = blockIdx.x * 1024 + tid * 4;
    int v[4]; int s = 0;
#pragma unroll
    for (int r = 0; r < 4; r++) {
        int i = base + r;
        v[r] = (i < N_NODES) ? indeg[i] : 0;
        s += v[r];
    }
    lds[tid] = s;
    __syncthreads();
    for (int off = 1; off < 256; off <<= 1) {
        int x = (tid >= off) ? lds[tid - off] : 0;
        __syncthreads();
        lds[tid] += x;
        __syncthreads();
    }
    int excl = lds[tid] - s;
    int w = excl;
#pragma unroll
    for (int r = 0; r < 4; r++) {
        int i = base + r;
        if (i < N_NODES) localscan[i] = w;
        w += v[r];
    }
    if (tid == 255) bsum[blockIdx.x] = lds[255];
}

__global__ void k_scan2(const int* __restrict__ bsum, int* __restrict__ boff, int nb) {
    if (threadIdx.x == 0 && blockIdx.x == 0) {
        int run = 0;
        for (int b = 0; b < nb; b++) { boff[b] = run; run += bsum[b]; }
    }
}

__global__ void k_scan3(int* __restrict__ rowstart, const int* __restrict__ boff) {
    int tid = threadIdx.x;
    int base = blockIdx.x * 1024 + tid * 4;
    int add = boff[blockIdx.x];
#pragma unroll
    for (int r = 0; r < 4; r++) {
        int i = base + r;
        if (i < N_NODES) rowstart[i] += add;
    }
    if (blockIdx.x == 0 && tid == 0) rowstart[N_NODES] = E_EDGES;
}

__global__ void k_fill(const int* __restrict__ src, const int* __restrict__ dst,
                       const int* __restrict__ et, const int* __restrict__ rowstart,
                       int* __restrict__ cursor, int* __restrict__ csr) {
    int e = blockIdx.x * blockDim.x + threadIdx.x;
    if (e >= E_EDGES) return;
    int d = dst[e];
    int pos = atomicAdd(&cursor[d], 1);
    csr[rowstart[d] + pos] = (src[e] & 0xFFFF) | (et[e] << 16);
}

// ---------------------------------------------------------------------------
// Aggregation (bf16 in/out, fp32 accum): z[n] = h[n] + sum relu(h[src]+eattr)
// one wave per node; lane owns dword lane (ch 2l,2l+1); lane 0 also dword 64
// ---------------------------------------------------------------------------
__device__ __forceinline__ void acc_edge(unsigned d, int t, int tl0, int tl1,
                                         float& a0, float& a1) {
    float lo = bflo(d) + ((t == tl0) ? 1.f : 0.f);
    float hi = bfhi(d) + ((t == tl1) ? 1.f : 0.f);
    a0 += fmaxf(lo, 0.f);
    a1 += fmaxf(hi, 0.f);
}
__device__ __forceinline__ void acc_tail(unsigned d, float& a2, float& a3) {
    a2 += fmaxf(bflo(d), 0.f);
    a3 += fmaxf(bfhi(d), 0.f);
}

__global__ __launch_bounds__(256) void k_spmm(const unsigned* __restrict__ h2,
                                              const int* __restrict__ rowstart,
                                              const int* __restrict__ csr,
                                              unsigned* __restrict__ z2) {
    int wave = threadIdx.x >> 6;
    int lane = threadIdx.x & 63;
    int n = blockIdx.x * 4 + wave;
    if (n >= N_NODES) return;
    int rs = rowstart[n], re = rowstart[n + 1];
    int tl0 = 2 * lane, tl1 = 2 * lane + 1;
    float a0 = 0.f, a1 = 0.f, a2 = 0.f, a3 = 0.f;
    int e = rs;
    for (; e + 4 <= re; e += 4) {
        int p0 = csr[e], p1 = csr[e + 1], p2 = csr[e + 2], p3 = csr[e + 3];
        unsigned s0 = (unsigned)(p0 & 0xFFFF), s1 = (unsigned)(p1 & 0xFFFF);
        unsigned s2 = (unsigned)(p2 & 0xFFFF), s3 = (unsigned)(p3 & 0xFFFF);
        unsigned d0 = h2[s0 * 80u + lane];
        unsigned d1 = h2[s1 * 80u + lane];
        unsigned d2 = h2[s2 * 80u + lane];
        unsigned d3 = h2[s3 * 80u + lane];
        if (lane == 0) {
            unsigned q0 = h2[s0 * 80u + 64];
            unsigned q1 = h2[s1 * 80u + 64];
            unsigned q2 = h2[s2 * 80u + 64];
            unsigned q3 = h2[s3 * 80u + 64];
            acc_tail(q0, a2, a3); acc_tail(q1, a2, a3);
            acc_tail(q2, a2, a3); acc_tail(q3, a2, a3);
        }
        acc_edge(d0, p0 >> 16, tl0, tl1, a0, a1);
        acc_edge(d1, p1 >> 16, tl0, tl1, a0, a1);
        acc_edge(d2, p2 >> 16, tl0, tl1, a0, a1);
        acc_edge(d3, p3 >> 16, tl0, tl1, a0, a1);
    }
    for (; e < re; ++e) {
        int p = csr[e];
        unsigned s = (unsigned)(p & 0xFFFF);
        unsigned d = h2[s * 80u + lane];
        if (lane == 0) acc_tail(h2[s * 80u + 64], a2, a3);
        acc_edge(d, p >> 16, tl0, tl1, a0, a1);
    }
    unsigned hn = h2[(unsigned)n * 80u + lane];
    z2[(unsigned)n * 80u + lane] = packbf(bflo(hn) + a0, bfhi(hn) + a1);
    if (lane == 0) {
        unsigned hq = h2[(unsigned)n * 80u + 64];
        z2[(unsigned)n * 80u + 64] = packbf(bflo(hq) + a2, bfhi(hq) + a3);
    } else if (lane < 16) {
        z2[(unsigned)n * 80u + 64 + lane] = 0;
    }
}

// ---------------------------------------------------------------------------
// MFMA GEMM: C[M][160](bf16) = relu( A[M][160](bf16) @ W * scale + shift )
// block = 256 thr = 4 waves; wave w: rows blk*32 + (w>>1)*16, cols (w&1)*80
// per wave: 5 ks x (A-frag + 5 x (B-frag + MFMA 16x16x32))
// ---------------------------------------------------------------------------
__global__ __launch_bounds__(256) void k_gemm_mfma(const unsigned short* __restrict__ A,
        const unsigned short* __restrict__ Bp, const float* __restrict__ scale,
        const float* __restrict__ shift, unsigned short* __restrict__ Cout, int M) {
    int tid = threadIdx.x;
    int w = tid >> 6, l = tid & 63;
    int mrow_blk = blockIdx.x * 32 + (w >> 1) * 16;
    int colh = (w & 1) * 80;
    int kg = l >> 4;
    int arow = mrow_blk + (l & 15);
    bool aok = arow < M;
    const unsigned short* abase = A + (size_t)arow * CP + kg * 8;
    f32x4 acc[5] = {};
    for (int ks = 0; ks < 5; ++ks) {
        union { bf16x8 v; uint4 u; } af;
        if (aok) af.u = *(const uint4*)(abase + ks * 32);
        else     af.u = make_uint4(0, 0, 0, 0);
        const unsigned short* bbase = Bp + ((size_t)((ks * 10 + (w & 1) * 5) * 64 + l)) * 8;
#pragma unroll
        for (int f = 0; f < 5; ++f) {
            union { bf16x8 v; uint4 u; } bf;
            bf.u = *(const uint4*)(bbase + (size_t)f * 64 * 8);
            acc[f] = __builtin_amdgcn_mfma_f32_16x16x32_bf16(af.v, bf.v, acc[f], 0, 0, 0);
        }
    }
    // epilogue: C/D layout col=lane&15, row=(lane>>4)*4+j
    int crow0 = mrow_blk + kg * 4;
    int cbase = colh + (l & 15);
#pragma unroll
    for (int f = 0; f < 5; ++f) {
        int c = cbase + f * 16;
        float sc = scale[c], sh = shift[c];
#pragma unroll
        for (int j = 0; j < 4; ++j) {
            int rr = crow0 + j;
            if (rr < M) {
                float v = fmaxf(fmaf(acc[f][j], sc, sh), 0.f);
                Cout[(size_t)rr * CP + c] = f2bf(v);
            }
        }
    }
}

// head second matmul: out[n][k] = sum_j u[n][j]*Wh2p[j][k] + bh2[k]   (no relu)
__global__ __launch_bounds__(256) void k_head2(const unsigned* __restrict__ u2,
                                               const float* __restrict__ W2p,
                                               const float* __restrict__ bh2,
                                               float* __restrict__ out) {
    int wave = threadIdx.x >> 6;
    int lane = threadIdx.x & 63;
    int n = blockIdx.x * 4 + wave;
    if (n >= N_NODES) return;
    unsigned d = u2[(unsigned)n * 80u + lane];
    float u0 = bflo(d), u1 = bfhi(d);
    float4 wv = *(const float4*)(W2p + 4 * lane);
    float p0 = u0 * wv.x + u1 * wv.z;
    float p1 = u0 * wv.y + u1 * wv.w;
    if (lane == 0) {
        unsigned dq = u2[(unsigned)n * 80u + 64];
        float4 wq = *(const float4*)(W2p + 4 * 64);
        p0 += bflo(dq) * wq.x + bfhi(dq) * wq.z;
        p1 += bflo(dq) * wq.y + bfhi(dq) * wq.w;
    }
#pragma unroll
    for (int off = 32; off > 0; off >>= 1) {
        p0 += __shfl_down(p0, off, 64);
        p1 += __shfl_down(p1, off, 64);
    }
    if (lane == 0) {
        out[n * 2 + 0] = p0 + bh2[0];
        out[n * 2 + 1] = p1 + bh2[1];
    }
}

// ---------------------------------------------------------------------------
extern "C" void kernel_launch(void* const* d_in, const int* in_sizes, int n_in,
                              void* d_out, int out_size, void* d_ws, size_t ws_size,
                              hipStream_t stream) {
    const int* x_type  = (const int*)d_in[0];
    const int* x_tok   = (const int*)d_in[1];
    const float* x_small = (const float*)d_in[2];
    const int* e_src   = (const int*)d_in[3];
    const int* e_dst   = e_src + E_EDGES;
    const int* e_type  = (const int*)d_in[4];
    const float* W1    = (const float*)d_in[6];
    const float* b1    = (const float*)d_in[7];
    const float* W2    = (const float*)d_in[8];
    const float* b2    = (const float*)d_in[9];
    const float* gamma = (const float*)d_in[10];
    const float* beta  = (const float*)d_in[11];
    const float* rmean = (const float*)d_in[12];
    const float* rvar  = (const float*)d_in[13];
    const float* Wh1   = (const float*)d_in[14];
    const float* bh1   = (const float*)d_in[15];
    const float* Wh2   = (const float*)d_in[16];
    const float* bh2   = (const float*)d_in[17];
    float* out = (float*)d_out;

    char* ws = (char*)d_ws;
    size_t o = 0;
    auto take = [&](size_t bytes) -> void* {
        void* p = ws + o;
        o = (o + bytes + 255) & ~(size_t)255;
        return p;
    };
    const size_t NODE_BUF = (size_t)N_NODES * CP * sizeof(unsigned short);  // 16 MB
    unsigned* bufA = (unsigned*)take(NODE_BUF);
    unsigned* bufB = (unsigned*)take(NODE_BUF);
    unsigned* bufC = (unsigned*)take(NODE_BUF);
    unsigned short* Bp = (unsigned short*)take((size_t)9 * 50 * 64 * 8 * sizeof(unsigned short));
    float* Wh2p = (float*)take((size_t)CP * 2 * sizeof(float));
    float* ss   = (float*)take((size_t)9 * 2 * CP * sizeof(float));
    int* indeg    = (int*)take((size_t)N_NODES * sizeof(int));
    int* cursor   = (int*)take((size_t)N_NODES * sizeof(int));
    int* rowstart = (int*)take((size_t)(N_NODES + 1) * sizeof(int));
    int* bsum     = (int*)take(64 * sizeof(int));
    int* boff     = (int*)take(64 * sizeof(int));
    int* csr      = (int*)take((size_t)E_EDGES * sizeof(int));
    (void)ws_size; (void)in_sizes; (void)n_in; (void)out_size;

    const int NB_SCAN = (N_NODES + 1023) / 1024;  // 49

    // weights / epilogue prep
    k_packB<<<450, 64, 0, stream>>>(W1, W2, Wh1, Bp);
    k_padWh2<<<1, 384, 0, stream>>>(Wh2, Wh2p);
    k_ss<<<9, 192, 0, stream>>>(b1, b2, gamma, beta, rmean, rvar, bh1, ss);

    // features (bf16)
    k_feat<<<(N_NODES * 80 + 255) / 256, 256, 0, stream>>>(x_type, x_tok, x_small, bufA);

    // CSR by dst
    k_zero_i32<<<(N_NODES + 255) / 256, 256, 0, stream>>>(indeg, N_NODES);
    k_zero_i32<<<(N_NODES + 255) / 256, 256, 0, stream>>>(cursor, N_NODES);
    k_indeg<<<(E_EDGES + 255) / 256, 256, 0, stream>>>(e_dst, indeg);
    k_scan1<<<NB_SCAN, 256, 0, stream>>>(indeg, rowstart, bsum);
    k_scan2<<<1, 64, 0, stream>>>(bsum, boff, NB_SCAN);
    k_scan3<<<NB_SCAN, 256, 0, stream>>>(rowstart, boff);
    k_fill<<<(E_EDGES + 255) / 256, 256, 0, stream>>>(e_src, e_dst, e_type, rowstart, cursor, csr);

    // layers
    const int GEMM_GRID = (N_NODES + 31) / 32;  // 1563
    for (int l = 0; l < L_LAYERS; l++) {
        k_spmm<<<(N_NODES + 3) / 4, 256, 0, stream>>>(bufA, rowstart, csr, bufB);
        int g1 = 2 * l, g2 = 2 * l + 1;
        k_gemm_mfma<<<GEMM_GRID, 256, 0, stream>>>((const unsigned short*)bufB,
            Bp + (size_t)g1 * 50 * 64 * 8, ss + (size_t)(2 * g1) * CP,
            ss + (size_t)(2 * g1 + 1) * CP, (unsigned short*)bufC, N_NODES);
        k_gemm_mfma<<<GEMM_GRID, 256, 0, stream>>>((const unsigned short*)bufC,
            Bp + (size_t)g2 * 50 * 64 * 8, ss + (size_t)(2 * g2) * CP,
            ss + (size_t)(2 * g2 + 1) * CP, (unsigned short*)bufA, N_NODES);
    }

    // head
    k_gemm_mfma<<<GEMM_GRID, 256, 0, stream>>>((const unsigned short*)bufA,
        Bp + (size_t)8 * 50 * 64 * 8, ss + (size_t)(2 * 8) * CP,
        ss + (size_t)(2 * 8 + 1) * CP, (unsigned short*)bufB, N_NODES);
    k_head2<<<(N_NODES + 3) / 4, 256, 0, stream>>>(bufB, Wh2p, bh2, out);
}

// Round 3
// 409.026 us; speedup vs baseline: 2.1806x; 1.0228x over previous
//
#include <hip/hip_runtime.h>
#include <hip/hip_bf16.h>

// Problem constants (match reference setup_inputs)
#define N_NODES 50000
#define E_EDGES 600000
#define C_CH    130
#define CP      160      // padded channel width for weights/frags
#define L_LAYERS 4
#define BN_EPS  1e-5f
#define TS      168      // LDS t-tile stride (ushorts)

typedef __bf16 bf16x8 __attribute__((ext_vector_type(8)));
typedef float  f32x4  __attribute__((ext_vector_type(4)));

// fp32 -> bf16 RNE
__device__ __forceinline__ unsigned short f2bf(float f) {
    unsigned u = __float_as_uint(f);
    unsigned r = (u + 0x7FFFu + ((u >> 16) & 1u)) >> 16;
    return (unsigned short)r;
}
__device__ __forceinline__ unsigned packbf(float lo, float hi) {
    return (unsigned)f2bf(lo) | ((unsigned)f2bf(hi) << 16);
}
__device__ __forceinline__ float bflo(unsigned d) { return __uint_as_float(d << 16); }
__device__ __forceinline__ float bfhi(unsigned d) { return __uint_as_float(d & 0xFFFF0000u); }

// ---------------------------------------------------------------------------
// utility / prep kernels
// ---------------------------------------------------------------------------
__global__ void k_zero_i32(int* p, int n) {
    int i = blockIdx.x * blockDim.x + threadIdx.x;
    for (; i < n; i += gridDim.x * blockDim.x) p[i] = 0;
}

// pad Wh2 [130][2] -> [160][2] fp32
__global__ void k_padWh2(const float* __restrict__ src, float* __restrict__ dst) {
    int i = threadIdx.x;
    if (i >= CP * 2) return;
    int r = i >> 1, c = i & 1;
    dst[i] = (r < C_CH) ? src[r * 2 + c] : 0.f;
}

// Per-GEMM epilogue scale/shift: ss[g][2][160], g = 0..8
__global__ void k_ss(const float* __restrict__ b1, const float* __restrict__ b2,
                     const float* __restrict__ gamma, const float* __restrict__ beta,
                     const float* __restrict__ rmean, const float* __restrict__ rvar,
                     const float* __restrict__ bh1, float* __restrict__ ss) {
    int g = blockIdx.x;
    int c = threadIdx.x;
    if (c >= CP) return;
    float scale = 1.f, shift = 0.f;
    if (g < 2 * L_LAYERS) {
        int l = g >> 1;
        if ((g & 1) == 0) {
            if (c < C_CH) shift = b1[l * C_CH + c];
        } else if (c < C_CH) {
            float s = gamma[l * C_CH + c] * rsqrtf(rvar[l * C_CH + c] + BN_EPS);
            scale = s;
            shift = (b2[l * C_CH + c] - rmean[l * C_CH + c]) * s + beta[l * C_CH + c];
        }
    } else {
        if (c < C_CH) shift = bh1[c];
    }
    ss[(g * 2 + 0) * CP + c] = scale;
    ss[(g * 2 + 1) * CP + c] = shift;
}

// Pack weights into MFMA B-fragment order, bf16.
// Bp[frag = g*50 + ks*10 + f][lane][j] = W_g[k = ks*32 + (lane>>4)*8 + j][c = f*16 + (lane&15)]
__global__ void k_packB(const float* __restrict__ W1, const float* __restrict__ W2,
                        const float* __restrict__ Wh1, unsigned short* __restrict__ Bp) {
    int blk = blockIdx.x;          // 0..449
    int g = blk / 50;
    int r = blk - g * 50;
    int ks = r / 10, f = r - ks * 10;
    int l = threadIdx.x;           // 0..63
    const float* W;
    if (g < 8) W = (g & 1) ? (W2 + (size_t)(g >> 1) * C_CH * C_CH)
                           : (W1 + (size_t)(g >> 1) * C_CH * C_CH);
    else       W = Wh1;
    int kg = l >> 4;
    int c = f * 16 + (l & 15);
    union { unsigned short s[8]; uint4 u; } out;
#pragma unroll
    for (int j = 0; j < 8; j++) {
        int k = ks * 32 + kg * 8 + j;
        float v = (k < C_CH && c < C_CH) ? W[k * C_CH + c] : 0.f;
        out.s[j] = f2bf(v);
    }
    *(uint4*)(Bp + ((size_t)(blk * 64 + l) * 8)) = out.u;
}

// features, main plane: hm[n][dw 0..63] = bf16 pair (ch 2d, 2d+1), one-hots only
__global__ void k_feat(const int* __restrict__ xt, const int* __restrict__ xk,
                       unsigned* __restrict__ hm) {
    int idx = blockIdx.x * blockDim.x + threadIdx.x;
    if (idx >= N_NODES * 64) return;
    int n = idx >> 6;
    int d = idx & 63;
    unsigned v = 0;
#pragma unroll
    for (int s = 0; s < 2; s++) {
        int c = 2 * d + s;
        float x = 0.f;
        if (c < 32) {
            x = (xt[n] == c) ? 1.f : 0.f;
        } else {
            int tk = xk[n];
            tk = tk < 0 ? 0 : (tk > 95 ? 95 : tk);
            x = (tk == c - 32) ? 1.f : 0.f;
        }
        v |= ((unsigned)f2bf(x)) << (16 * s);
    }
    hm[idx] = v;
}

// features, tail plane: ht = (ch128,ch129) = x_small; htm = relu'd copy (msg side, layer 0)
__global__ void k_feat_tail(const float* __restrict__ xs, unsigned* __restrict__ ht,
                            unsigned* __restrict__ htm) {
    int n = blockIdx.x * blockDim.x + threadIdx.x;
    if (n >= N_NODES) return;
    float a = xs[2 * n], b = xs[2 * n + 1];
    ht[n]  = packbf(a, b);
    htm[n] = packbf(fmaxf(a, 0.f), fmaxf(b, 0.f));
}

// ---------------------------------------------------------------------------
// CSR-by-dst build
// ---------------------------------------------------------------------------
__global__ void k_indeg(const int* __restrict__ dst, int* __restrict__ indeg) {
    int e = blockIdx.x * blockDim.x + threadIdx.x;
    if (e < E_EDGES) atomicAdd(&indeg[dst[e]], 1);
}

__global__ void k_scan1(const int* __restrict__ indeg, int* __restrict__ localscan,
                        int* __restrict__ bsum) {
    __shared__ int lds[256];
    int tid = threadIdx.x;
    int base = blockIdx.x * 1024 + tid * 4;
    int v[4]; int s = 0;
#pragma unroll
    for (int r = 0; r < 4; r++) {
        int i = base + r;
        v[r] = (i < N_NODES) ? indeg[i] : 0;
        s += v[r];
    }
    lds[tid] = s;
    __syncthreads();
    for (int off = 1; off < 256; off <<= 1) {
        int x = (tid >= off) ? lds[tid - off] : 0;
        __syncthreads();
        lds[tid] += x;
        __syncthreads();
    }
    int excl = lds[tid] - s;
    int w = excl;
#pragma unroll
    for (int r = 0; r < 4; r++) {
        int i = base + r;
        if (i < N_NODES) localscan[i] = w;
        w += v[r];
    }
    if (tid == 255) bsum[blockIdx.x] = lds[255];
}

__global__ void k_scan2(const int* __restrict__ bsum, int* __restrict__ boff, int nb) {
    if (threadIdx.x == 0 && blockIdx.x == 0) {
        int run = 0;
        for (int b = 0; b < nb; b++) { boff[b] = run; run += bsum[b]; }
    }
}

__global__ void k_scan3(int* __restrict__ rowstart, const int* __restrict__ boff) {
    int tid = threadIdx.x;
    int base = blockIdx.x * 1024 + tid * 4;
    int add = boff[blockIdx.x];
#pragma unroll
    for (int r = 0; r < 4; r++) {
        int i = base + r;
        if (i < N_NODES) rowstart[i] += add;
    }
    if (blockIdx.x == 0 && tid == 0) rowstart[N_NODES] = E_EDGES;
}

__global__ void k_fill(const int* __restrict__ src, const int* __restrict__ dst,
                       const int* __restrict__ et, const int* __restrict__ rowstart,
                       int* __restrict__ cursor, int* __restrict__ csr) {
    int e = blockIdx.x * blockDim.x + threadIdx.x;
    if (e >= E_EDGES) return;
    int d = dst[e];
    int pos = atomicAdd(&cursor[d], 1);
    csr[rowstart[d] + pos] = (src[e] & 0xFFFF) | (et[e] << 16);
}

// per-node edge-type counts (once; layer-invariant): cntf[n] = {#t0, #t1, #t2, 0}
__global__ void k_cnt(const int* __restrict__ rowstart, const int* __restrict__ csr,
                      float4* __restrict__ cntf) {
    int n = blockIdx.x * blockDim.x + threadIdx.x;
    if (n >= N_NODES) return;
    int c0 = 0, c1 = 0, c2 = 0;
    for (int e = rowstart[n]; e < rowstart[n + 1]; ++e) {
        int t = csr[e] >> 16;
        c0 += (t == 0); c1 += (t == 1); c2 += (t == 2);
    }
    cntf[n] = make_float4((float)c0, (float)c1, (float)c2, 0.f);
}

// ---------------------------------------------------------------------------
// Linearized aggregation, main plane (ch 0..127):
//   zm[n] = hm[n] + sum_e hm[src_e] + cnt(n) on ch 0..2
// one wave per node; lane owns dword `lane`; masked 8-wide unroll
// ---------------------------------------------------------------------------
__global__ __launch_bounds__(256) void k_spmm(const unsigned* __restrict__ hm,
                                              const int* __restrict__ rowstart,
                                              const int* __restrict__ csr,
                                              const float4* __restrict__ cntf,
                                              unsigned* __restrict__ zm) {
    int wave = threadIdx.x >> 6;
    int lane = threadIdx.x & 63;
    int n = blockIdx.x * 4 + wave;
    if (n >= N_NODES) return;
    int rs = rowstart[n], re = rowstart[n + 1];
    float a0 = 0.f, a1 = 0.f;
    for (int e = rs; e < re; e += 8) {
        unsigned d[8];
#pragma unroll
        for (int r = 0; r < 8; r++) {
            int ee = (e + r < re) ? (e + r) : (re - 1);
            unsigned s = (unsigned)(csr[ee] & 0xFFFF);
            d[r] = hm[s * 64u + lane];
        }
#pragma unroll
        for (int r = 0; r < 8; r++) {
            if (e + r < re) { a0 += bflo(d[r]); a1 += bfhi(d[r]); }
        }
    }
    unsigned hn = hm[(unsigned)n * 64u + lane];
    a0 += bflo(hn); a1 += bfhi(hn);
    if (lane < 2) {
        float4 c = cntf[n];
        if (lane == 0) { a0 += c.x; a1 += c.y; }
        else           { a0 += c.z; }
    }
    zm[(unsigned)n * 64u + lane] = packbf(a0, a1);
}

// tail plane (ch 128/129): zt[n] = ht[n] + sum_e htm[src_e]; node-per-thread
__global__ void k_spmm_tail(const unsigned* __restrict__ htm, const unsigned* __restrict__ ht,
                            const int* __restrict__ rowstart, const int* __restrict__ csr,
                            unsigned* __restrict__ zt) {
    int n = blockIdx.x * blockDim.x + threadIdx.x;
    if (n >= N_NODES) return;
    unsigned hn = ht[n];
    float a0 = bflo(hn), a1 = bfhi(hn);
    for (int e = rowstart[n]; e < rowstart[n + 1]; ++e) {
        unsigned d = htm[csr[e] & 0xFFFF];
        a0 += bflo(d); a1 += bfhi(d);
    }
    zt[n] = packbf(a0, a1);
}

// ---------------------------------------------------------------------------
// Fused MLP layer: h_out = relu(BN(relu(z@W1+b1)@W2+b2))
// block=256 (4 waves), 64 rows; wave w: row-group (w>>1), col-half (w&1),
// two row-sets (s=0: rows+0, s=1: rows+32); 50 MFMA per wave per stage
// ---------------------------------------------------------------------------
__global__ __launch_bounds__(256) void k_mlp(const unsigned* __restrict__ zm,
        const unsigned* __restrict__ zt,
        const unsigned short* __restrict__ Bp1, const unsigned short* __restrict__ Bp2,
        const float* __restrict__ sh1, const float* __restrict__ sc2,
        const float* __restrict__ sh2,
        unsigned* __restrict__ hm, unsigned* __restrict__ ht, int M) {
    __shared__ unsigned short t_lds[64 * TS];
    int tid = threadIdx.x;
    int w = tid >> 6, l = tid & 63;
    int rowg = w >> 1;
    int chh = w & 1;
    int ch = chh * 80;
    int kg = l >> 4;
    int lr = l & 15;
    int mbase = blockIdx.x * 64;
    int r0 = mbase + rowg * 16 + lr;
    int r1 = r0 + 32;
    bool ok0 = r0 < M, ok1 = r1 < M;

    f32x4 acc0[5] = {}, acc1[5] = {};
    // ---- stage 1: z @ W1 ----
    const unsigned* a0p = zm + (size_t)r0 * 64 + kg * 4;
    const unsigned* a1p = zm + (size_t)r1 * 64 + kg * 4;
    for (int ks = 0; ks < 5; ++ks) {
        union { bf16x8 v; uint4 u; } af0, af1;
        if (ks < 4) {
            af0.u = ok0 ? *(const uint4*)(a0p + ks * 16) : make_uint4(0, 0, 0, 0);
            af1.u = ok1 ? *(const uint4*)(a1p + ks * 16) : make_uint4(0, 0, 0, 0);
        } else {
            af0.u = make_uint4((kg == 0 && ok0) ? zt[r0] : 0u, 0, 0, 0);
            af1.u = make_uint4((kg == 0 && ok1) ? zt[r1] : 0u, 0, 0, 0);
        }
        const unsigned short* bb = Bp1 + ((size_t)((ks * 10 + chh * 5) * 64 + l)) * 8;
#pragma unroll
        for (int f = 0; f < 5; ++f) {
            union { bf16x8 v; uint4 u; } bf;
            bf.u = *(const uint4*)(bb + (size_t)f * 512);
            acc0[f] = __builtin_amdgcn_mfma_f32_16x16x32_bf16(af0.v, bf.v, acc0[f], 0, 0, 0);
            acc1[f] = __builtin_amdgcn_mfma_f32_16x16x32_bf16(af1.v, bf.v, acc1[f], 0, 0, 0);
        }
    }
    // epilogue1: t = relu(acc + b1) -> LDS (bf16)
    {
        int rl0 = rowg * 16 + kg * 4;
#pragma unroll
        for (int f = 0; f < 5; ++f) {
            int c = ch + lr + f * 16;
            float sh = sh1[c];
#pragma unroll
            for (int j = 0; j < 4; ++j) {
                t_lds[(rl0 + j) * TS + c]      = f2bf(fmaxf(acc0[f][j] + sh, 0.f));
                t_lds[(rl0 + 32 + j) * TS + c] = f2bf(fmaxf(acc1[f][j] + sh, 0.f));
            }
        }
    }
    __syncthreads();
    // ---- stage 2: t @ W2, BN fold, relu ----
#pragma unroll
    for (int f = 0; f < 5; ++f) { acc0[f] = (f32x4){0,0,0,0}; acc1[f] = (f32x4){0,0,0,0}; }
    int lrow0 = rowg * 16 + lr;
    for (int ks = 0; ks < 5; ++ks) {
        union { bf16x8 v; uint4 u; } af0, af1;
        af0.u = *(const uint4*)(t_lds + (size_t)lrow0 * TS + ks * 32 + kg * 8);
        af1.u = *(const uint4*)(t_lds + (size_t)(lrow0 + 32) * TS + ks * 32 + kg * 8);
        const unsigned short* bb = Bp2 + ((size_t)((ks * 10 + chh * 5) * 64 + l)) * 8;
#pragma unroll
        for (int f = 0; f < 5; ++f) {
            union { bf16x8 v; uint4 u; } bf;
            bf.u = *(const uint4*)(bb + (size_t)f * 512);
            acc0[f] = __builtin_amdgcn_mfma_f32_16x16x32_bf16(af0.v, bf.v, acc0[f], 0, 0, 0);
            acc1[f] = __builtin_amdgcn_mfma_f32_16x16x32_bf16(af1.v, bf.v, acc1[f], 0, 0, 0);
        }
    }
    // epilogue2 -> split global planes (only real channels)
    int grow0 = mbase + rowg * 16 + kg * 4;
#pragma unroll
    for (int f = 0; f < 5; ++f) {
        int c = ch + lr + f * 16;
        if (c >= C_CH) continue;
        float sc = sc2[c], sh = sh2[c];
#pragma unroll
        for (int j = 0; j < 4; ++j) {
            int rr0 = grow0 + j, rr1 = rr0 + 32;
            unsigned short v0 = f2bf(fmaxf(fmaf(acc0[f][j], sc, sh), 0.f));
            unsigned short v1 = f2bf(fmaxf(fmaf(acc1[f][j], sc, sh), 0.f));
            if (c < 128) {
                if (rr0 < M) ((unsigned short*)hm)[(size_t)rr0 * 128 + c] = v0;
                if (rr1 < M) ((unsigned short*)hm)[(size_t)rr1 * 128 + c] = v1;
            } else {
                if (rr0 < M) ((unsigned short*)ht)[(size_t)rr0 * 2 + (c - 128)] = v0;
                if (rr1 < M) ((unsigned short*)ht)[(size_t)rr1 * 2 + (c - 128)] = v1;
            }
        }
    }
}

// ---------------------------------------------------------------------------
// Fused head: out = relu(h@Wh1+bh1) @ Wh2 + bh2   [N,2] fp32
// stage1 like k_mlp stage1 (g=8), then per-lane dot with Wh2 + shuffle reduce
// ---------------------------------------------------------------------------
__global__ __launch_bounds__(256) void k_head(const unsigned* __restrict__ hm,
        const unsigned* __restrict__ ht, const unsigned short* __restrict__ Bp8,
        const float* __restrict__ sh1, const float* __restrict__ Wh2p,
        const float* __restrict__ bh2, float* __restrict__ out, int M) {
    __shared__ float red[64][2][2];
    int tid = threadIdx.x;
    int w = tid >> 6, l = tid & 63;
    int rowg = w >> 1;
    int chh = w & 1;
    int ch = chh * 80;
    int kg = l >> 4;
    int lr = l & 15;
    int mbase = blockIdx.x * 64;
    int r0 = mbase + rowg * 16 + lr;
    int r1 = r0 + 32;
    bool ok0 = r0 < M, ok1 = r1 < M;

    f32x4 acc0[5] = {}, acc1[5] = {};
    const unsigned* a0p = hm + (size_t)r0 * 64 + kg * 4;
    const unsigned* a1p = hm + (size_t)r1 * 64 + kg * 4;
    for (int ks = 0; ks < 5; ++ks) {
        union { bf16x8 v; uint4 u; } af0, af1;
        if (ks < 4) {
            af0.u = ok0 ? *(const uint4*)(a0p + ks * 16) : make_uint4(0, 0, 0, 0);
            af1.u = ok1 ? *(const uint4*)(a1p + ks * 16) : make_uint4(0, 0, 0, 0);
        } else {
            af0.u = make_uint4((kg == 0 && ok0) ? ht[r0] : 0u, 0, 0, 0);
            af1.u = make_uint4((kg == 0 && ok1) ? ht[r1] : 0u, 0, 0, 0);
        }
        const unsigned short* bb = Bp8 + ((size_t)((ks * 10 + chh * 5) * 64 + l)) * 8;
#pragma unroll
        for (int f = 0; f < 5; ++f) {
            union { bf16x8 v; uint4 u; } bf;
            bf.u = *(const uint4*)(bb + (size_t)f * 512);
            acc0[f] = __builtin_amdgcn_mfma_f32_16x16x32_bf16(af0.v, bf.v, acc0[f], 0, 0, 0);
            acc1[f] = __builtin_amdgcn_mfma_f32_16x16x32_bf16(af1.v, bf.v, acc1[f], 0, 0, 0);
        }
    }
    // u = relu(acc+bh1); partial dot with Wh2 (per-lane over its 5 cols)
    float p0[4][2] = {}, p1[4][2] = {};
#pragma unroll
    for (int f = 0; f < 5; ++f) {
        int c = ch + lr + f * 16;
        float sh = sh1[c];
        float w0 = Wh2p[c * 2], w1 = Wh2p[c * 2 + 1];
#pragma unroll
        for (int j = 0; j < 4; ++j) {
            float u0 = fmaxf(acc0[f][j] + sh, 0.f);
            float u1 = fmaxf(acc1[f][j] + sh, 0.f);
            p0[j][0] = fmaf(u0, w0, p0[j][0]); p0[j][1] = fmaf(u0, w1, p0[j][1]);
            p1[j][0] = fmaf(u1, w0, p1[j][0]); p1[j][1] = fmaf(u1, w1, p1[j][1]);
        }
    }
    // reduce over 16 lanes (col dimension) within each kg group
#pragma unroll
    for (int m = 1; m < 16; m <<= 1) {
#pragma unroll
        for (int j = 0; j < 4; ++j) {
#pragma unroll
            for (int k = 0; k < 2; ++k) {
                p0[j][k] += __shfl_xor(p0[j][k], m, 64);
                p1[j][k] += __shfl_xor(p1[j][k], m, 64);
            }
        }
    }
    if (lr == 0) {
        int rl = rowg * 16 + kg * 4;
#pragma unroll
        for (int j = 0; j < 4; ++j) {
            red[rl + j][chh][0] = p0[j][0];      red[rl + j][chh][1] = p0[j][1];
            red[rl + 32 + j][chh][0] = p1[j][0]; red[rl + 32 + j][chh][1] = p1[j][1];
        }
    }
    __syncthreads();
    if (tid < 128) {
        int r = tid >> 1, k = tid & 1;
        int gr = mbase + r;
        if (gr < M) out[gr * 2 + k] = red[r][0][k] + red[r][1][k] + bh2[k];
    }
}

// ---------------------------------------------------------------------------
extern "C" void kernel_launch(void* const* d_in, const int* in_sizes, int n_in,
                              void* d_out, int out_size, void* d_ws, size_t ws_size,
                              hipStream_t stream) {
    const int* x_type  = (const int*)d_in[0];
    const int* x_tok   = (const int*)d_in[1];
    const float* x_small = (const float*)d_in[2];
    const int* e_src   = (const int*)d_in[3];
    const int* e_dst   = e_src + E_EDGES;
    const int* e_type  = (const int*)d_in[4];
    const float* W1    = (const float*)d_in[6];
    const float* b1    = (const float*)d_in[7];
    const float* W2    = (const float*)d_in[8];
    const float* b2    = (const float*)d_in[9];
    const float* gamma = (const float*)d_in[10];
    const float* beta  = (const float*)d_in[11];
    const float* rmean = (const float*)d_in[12];
    const float* rvar  = (const float*)d_in[13];
    const float* Wh1   = (const float*)d_in[14];
    const float* bh1   = (const float*)d_in[15];
    const float* Wh2   = (const float*)d_in[16];
    const float* bh2   = (const float*)d_in[17];
    float* out = (float*)d_out;

    char* ws = (char*)d_ws;
    size_t o = 0;
    auto take = [&](size_t bytes) -> void* {
        void* p = ws + o;
        o = (o + bytes + 255) & ~(size_t)255;
        return p;
    };
    const size_t HM_BUF = (size_t)N_NODES * 64 * sizeof(unsigned);  // 12.8 MB
    unsigned* hmA = (unsigned*)take(HM_BUF);
    unsigned* hmZ = (unsigned*)take(HM_BUF);
    unsigned* htA = (unsigned*)take((size_t)N_NODES * 4);
    unsigned* htZ = (unsigned*)take((size_t)N_NODES * 4);
    unsigned* htM0 = (unsigned*)take((size_t)N_NODES * 4);
    unsigned short* Bp = (unsigned short*)take((size_t)9 * 50 * 64 * 8 * sizeof(unsigned short));
    float* Wh2p = (float*)take((size_t)CP * 2 * sizeof(float));
    float* ss   = (float*)take((size_t)9 * 2 * CP * sizeof(float));
    float4* cntf  = (float4*)take((size_t)N_NODES * sizeof(float4));
    int* indeg    = (int*)take((size_t)N_NODES * sizeof(int));
    int* cursor   = (int*)take((size_t)N_NODES * sizeof(int));
    int* rowstart = (int*)take((size_t)(N_NODES + 1) * sizeof(int));
    int* bsum     = (int*)take(64 * sizeof(int));
    int* boff     = (int*)take(64 * sizeof(int));
    int* csr      = (int*)take((size_t)E_EDGES * sizeof(int));
    (void)ws_size; (void)in_sizes; (void)n_in; (void)out_size;

    const int NB_SCAN = (N_NODES + 1023) / 1024;  // 49

    // weights / epilogue prep
    k_packB<<<450, 64, 0, stream>>>(W1, W2, Wh1, Bp);
    k_padWh2<<<1, 384, 0, stream>>>(Wh2, Wh2p);
    k_ss<<<9, 192, 0, stream>>>(b1, b2, gamma, beta, rmean, rvar, bh1, ss);

    // features (split planes)
    k_feat<<<(N_NODES * 64 + 255) / 256, 256, 0, stream>>>(x_type, x_tok, hmA);
    k_feat_tail<<<(N_NODES + 255) / 256, 256, 0, stream>>>(x_small, htA, htM0);

    // CSR by dst + per-node etype counts
    k_zero_i32<<<(N_NODES + 255) / 256, 256, 0, stream>>>(indeg, N_NODES);
    k_zero_i32<<<(N_NODES + 255) / 256, 256, 0, stream>>>(cursor, N_NODES);
    k_indeg<<<(E_EDGES + 255) / 256, 256, 0, stream>>>(e_dst, indeg);
    k_scan1<<<NB_SCAN, 256, 0, stream>>>(indeg, rowstart, bsum);
    k_scan2<<<1, 64, 0, stream>>>(bsum, boff, NB_SCAN);
    k_scan3<<<NB_SCAN, 256, 0, stream>>>(rowstart, boff);
    k_fill<<<(E_EDGES + 255) / 256, 256, 0, stream>>>(e_src, e_dst, e_type, rowstart, cursor, csr);
    k_cnt<<<(N_NODES + 255) / 256, 256, 0, stream>>>(rowstart, csr, cntf);

    // layers
    const int MLP_GRID = (N_NODES + 63) / 64;  // 782
    for (int l = 0; l < L_LAYERS; l++) {
        int g1 = 2 * l, g2 = 2 * l + 1;
        k_spmm<<<(N_NODES + 3) / 4, 256, 0, stream>>>(hmA, rowstart, csr, cntf, hmZ);
        k_spmm_tail<<<(N_NODES + 255) / 256, 256, 0, stream>>>(l == 0 ? htM0 : htA, htA,
                                                               rowstart, csr, htZ);
        k_mlp<<<MLP_GRID, 256, 0, stream>>>(hmZ, htZ,
            Bp + (size_t)g1 * 25600, Bp + (size_t)g2 * 25600,
            ss + (size_t)(2 * g1 + 1) * CP,
            ss + (size_t)(2 * g2) * CP, ss + (size_t)(2 * g2 + 1) * CP,
            hmA, htA, N_NODES);
    }

    // fused head
    k_head<<<MLP_GRID, 256, 0, stream>>>(hmA, htA, Bp + (size_t)8 * 25600,
        ss + (size_t)(2 * 8 + 1) * CP, Wh2p, bh2, out, N_NODES);
}